// Round 1
// baseline (1594.508 us; speedup 1.0000x reference)
//
#include <hip/hip_runtime.h>
#include <hip/hip_bf16.h>
#include <math.h>

// Problem: B=2, S=2048, D=4096, H=32, KV=8, HD=128, N_REP=4, theta=1e6
// Inputs (fp32 unless noted): hidden(2,2048,4096), position_ids(int32 2,2048),
//   wq(4096,4096), bq(4096), wk(4096,1024), bk(1024), wv(4096,1024), bv(1024),
//   wo(4096,4096). Output fp32 (2,2048,4096).

typedef __bf16 bf16;
typedef __attribute__((ext_vector_type(8))) __bf16 bf16x8;
typedef __attribute__((ext_vector_type(4))) float f32x4;

// ---------------------------------------------------------------------------
// GEMM: C[M=4096, N] = A[4096, 4096] * W[4096, N] (+ bias), bf16 MFMA 16x16x32
// Tile 128x128, BK=32, 256 threads = 4 waves in 2x2, each wave 64x64 (4x4 MFMAs).
// MODE 0: A fp32 (hidden) -> q/k/v bf16 outputs (n-tile selects tensor), +bias
// MODE 1: A bf16 (attn out) -> fp32 output (d_out), W = wo, no bias
// ---------------------------------------------------------------------------
template <int MODE>
__global__ __launch_bounds__(256) void gemm_kernel(
    const float* __restrict__ A_f32, const bf16* __restrict__ A_bf16,
    const float* __restrict__ w_q, const float* __restrict__ b_q,
    const float* __restrict__ w_k, const float* __restrict__ b_k,
    const float* __restrict__ w_v, const float* __restrict__ b_v,
    bf16* __restrict__ q_out, bf16* __restrict__ k_out, bf16* __restrict__ v_out,
    float* __restrict__ f_out)
{
    __shared__ bf16 Asl[128 * 40];  // [row][k], stride 40 (pad) -> 2-way max
    __shared__ bf16 Bsl[128 * 40];  // transposed: [n][k], stride 40

    const int nt = blockIdx.x, mt = blockIdx.y;
    const int tid = threadIdx.x;
    const int wave = tid >> 6, lane = tid & 63;
    const int l15 = lane & 15, quad = lane >> 4;
    const int wm = (wave >> 1) * 64, wn = (wave & 1) * 64;

    const float* Bw;
    const float* bias = nullptr;
    bf16* outb = nullptr;
    int ldb, ldc, ncol0;
    if (MODE == 0) {
        if (nt < 32)      { Bw = w_q; bias = b_q; outb = q_out; ldb = 4096; ldc = 4096; ncol0 = nt * 128; }
        else if (nt < 40) { Bw = w_k; bias = b_k; outb = k_out; ldb = 1024; ldc = 1024; ncol0 = (nt - 32) * 128; }
        else              { Bw = w_v; bias = b_v; outb = v_out; ldb = 1024; ldc = 1024; ncol0 = (nt - 40) * 128; }
    } else {
        Bw = w_q; ldb = 4096; ldc = 4096; ncol0 = nt * 128;
    }
    const int row0 = mt * 128;

    const f32x4 vzero = {0.f, 0.f, 0.f, 0.f};
    f32x4 acc[4][4];
#pragma unroll
    for (int mi = 0; mi < 4; ++mi)
#pragma unroll
        for (int ni = 0; ni < 4; ++ni) acc[mi][ni] = vzero;

    const int a_row = tid >> 1, a_seg = (tid & 1) * 16;   // A: 128 rows x 2 segs of 16
    const int b_kk = tid >> 3, b_seg = (tid & 7) * 16;    // B: 32 k-rows x 8 segs of 16

    for (int k0 = 0; k0 < 4096; k0 += 32) {
        // ---- stage A tile (128x32) ----
        if (MODE == 0) {
            const float4* src = (const float4*)(A_f32 + (size_t)(row0 + a_row) * 4096 + k0 + a_seg);
            float4 f0 = src[0], f1 = src[1], f2 = src[2], f3 = src[3];
            bf16x8 p0, p1;
            p0[0] = (bf16)f0.x; p0[1] = (bf16)f0.y; p0[2] = (bf16)f0.z; p0[3] = (bf16)f0.w;
            p0[4] = (bf16)f1.x; p0[5] = (bf16)f1.y; p0[6] = (bf16)f1.z; p0[7] = (bf16)f1.w;
            p1[0] = (bf16)f2.x; p1[1] = (bf16)f2.y; p1[2] = (bf16)f2.z; p1[3] = (bf16)f2.w;
            p1[4] = (bf16)f3.x; p1[5] = (bf16)f3.y; p1[6] = (bf16)f3.z; p1[7] = (bf16)f3.w;
            *(bf16x8*)(&Asl[a_row * 40 + a_seg]) = p0;
            *(bf16x8*)(&Asl[a_row * 40 + a_seg + 8]) = p1;
        } else {
            const bf16x8* src = (const bf16x8*)(A_bf16 + (size_t)(row0 + a_row) * 4096 + k0 + a_seg);
            *(bf16x8*)(&Asl[a_row * 40 + a_seg]) = src[0];
            *(bf16x8*)(&Asl[a_row * 40 + a_seg + 8]) = src[1];
        }
        // ---- stage B tile (32x128), transposed into [n][k] ----
        {
            const float4* src = (const float4*)(Bw + (size_t)(k0 + b_kk) * ldb + ncol0 + b_seg);
            float4 g0 = src[0], g1 = src[1], g2 = src[2], g3 = src[3];
            float gv[16] = {g0.x, g0.y, g0.z, g0.w, g1.x, g1.y, g1.z, g1.w,
                            g2.x, g2.y, g2.z, g2.w, g3.x, g3.y, g3.z, g3.w};
#pragma unroll
            for (int i = 0; i < 16; ++i)
                Bsl[(b_seg + i) * 40 + b_kk] = (bf16)gv[i];
        }
        __syncthreads();

        bf16x8 af[4], bfv[4];
#pragma unroll
        for (int mi = 0; mi < 4; ++mi)
            af[mi] = *(const bf16x8*)(&Asl[(wm + mi * 16 + l15) * 40 + quad * 8]);
#pragma unroll
        for (int ni = 0; ni < 4; ++ni)
            bfv[ni] = *(const bf16x8*)(&Bsl[(wn + ni * 16 + l15) * 40 + quad * 8]);
#pragma unroll
        for (int mi = 0; mi < 4; ++mi)
#pragma unroll
            for (int ni = 0; ni < 4; ++ni)
                acc[mi][ni] = __builtin_amdgcn_mfma_f32_16x16x32_bf16(af[mi], bfv[ni], acc[mi][ni], 0, 0, 0);
        __syncthreads();
    }

    // ---- epilogue: C row = quad*4+reg, col = l15 (m89-verified layout) ----
#pragma unroll
    for (int mi = 0; mi < 4; ++mi)
#pragma unroll
        for (int ni = 0; ni < 4; ++ni)
#pragma unroll
            for (int i = 0; i < 4; ++i) {
                const int gr = row0 + wm + mi * 16 + quad * 4 + i;
                const int gc = ncol0 + wn + ni * 16 + l15;
                float vv = acc[mi][ni][i];
                if (MODE == 0) {
                    vv += bias[gc];
                    outb[(size_t)gr * ldc + gc] = (bf16)vv;
                } else {
                    f_out[(size_t)gr * ldc + gc] = vv;
                }
            }
}

// ---------------------------------------------------------------------------
// RoPE + transpose [B*S, NH*128] -> [B, NH, S, 128]; scale folded in (Q only).
// One thread per (b, h, s, d<64) handles the rotation pair (d, d+64).
// ---------------------------------------------------------------------------
template <int NH, int NHLOG>
__global__ __launch_bounds__(256) void rope_kernel(
    const bf16* __restrict__ xin, const int* __restrict__ pos_ids,
    bf16* __restrict__ xout, float scale)
{
    const size_t idx = (size_t)blockIdx.x * 256 + threadIdx.x;
    const int d = (int)(idx & 63);
    const size_t t1 = idx >> 6;
    const int s = (int)(t1 & 2047);
    const size_t t2 = t1 >> 11;
    const int hh = (int)(t2 & (NH - 1));
    const int b = (int)(t2 >> NHLOG);

    const float posv = (float)pos_ids[b * 2048 + s];
    // freq = theta^(-d/64) = 2^(-d * log2(1e6)/64)
    const float fr = exp2f((float)d * (-19.931568569324174f / 64.f));
    float sn, cs;
    sincosf(posv * fr, &sn, &cs);

    const bf16* xp = xin + ((size_t)(b * 2048 + s) * NH + hh) * 128 + d;
    const float x1 = (float)xp[0], x2 = (float)xp[64];
    bf16* op = xout + (((size_t)(b * NH + hh) * 2048) + s) * 128 + d;
    op[0]  = (bf16)((x1 * cs - x2 * sn) * scale);
    op[64] = (bf16)((x1 * sn + x2 * cs) * scale);
}

// V: [B*S, KV*128] -> [B, KV, S, 128]
__global__ __launch_bounds__(256) void conv_v_kernel(
    const bf16* __restrict__ v_pre, bf16* __restrict__ v_out)
{
    const size_t idx = (size_t)blockIdx.x * 256 + threadIdx.x;
    const int d = (int)(idx & 127);
    const int s = (int)((idx >> 7) & 2047);
    const int kvh = (int)((idx >> 18) & 7);
    const int b = (int)(idx >> 21);
    v_out[idx] = v_pre[((size_t)(b * 2048 + s) * 8 + kvh) * 128 + d];
}

// ---------------------------------------------------------------------------
// Flash attention, causal, GQA (4 q-heads per kv-head), bf16 MFMA 16x16x32.
// Block = 256 threads = 4 waves; each wave owns 16 q rows (BQ=64/block).
// KV tiles of 64. Online softmax in C-layout; P -> A-layout via LDS (m120).
// Q already scaled by 1/sqrt(128) in rope_kernel.
// ---------------------------------------------------------------------------
__global__ __launch_bounds__(256) void attn_kernel(
    const bf16* __restrict__ q, const bf16* __restrict__ k,
    const bf16* __restrict__ v, bf16* __restrict__ o)
{
    __shared__ bf16 Ksl[64 * 136];      // [kv][d], stride 136
    __shared__ bf16 Vsl[128 * 72];      // transposed [d][kv], stride 72
    __shared__ bf16 Psl[4 * 16 * 72];   // per-wave [qrow][kv], stride 72

    const int qt = blockIdx.x & 31;
    const int h  = (blockIdx.x >> 5) & 31;
    const int b  = blockIdx.x >> 10;
    const int kvh = h >> 2;
    const int tid = threadIdx.x;
    const int wave = tid >> 6, lane = tid & 63;
    const int l15 = lane & 15, quad = lane >> 4;

    // Q fragments (A-layout: row=l15, k=quad*8+j), 16 rows x 128 d per wave
    const bf16* qrow = q + (((size_t)(b * 32 + h) * 2048) + qt * 64 + wave * 16 + l15) * 128;
    bf16x8 qf[4];
#pragma unroll
    for (int kb = 0; kb < 4; ++kb)
        qf[kb] = *(const bf16x8*)(qrow + kb * 32 + quad * 8);

    const f32x4 vzero = {0.f, 0.f, 0.f, 0.f};
    f32x4 acc_o[8];
#pragma unroll
    for (int i = 0; i < 8; ++i) acc_o[i] = vzero;
    float m_i[4], l_i[4];
#pragma unroll
    for (int i = 0; i < 4; ++i) { m_i[i] = -INFINITY; l_i[i] = 0.f; }

    const bf16* kbase = k + (size_t)(b * 8 + kvh) * 2048 * 128;
    const bf16* vbase = v + (size_t)(b * 8 + kvh) * 2048 * 128;

    const int r = tid >> 2, sg = (tid & 3) * 32;  // staging: 64 rows x 4 segs of 32

    for (int t = 0; t <= qt; ++t) {
        const int kv0 = t * 64;
        // ---- stage K row-major, V transposed ----
        {
            const bf16x8* ks = (const bf16x8*)(kbase + (size_t)(kv0 + r) * 128 + sg);
            bf16x8* kd = (bf16x8*)(&Ksl[r * 136 + sg]);
            kd[0] = ks[0]; kd[1] = ks[1]; kd[2] = ks[2]; kd[3] = ks[3];
            const bf16x8* vs = (const bf16x8*)(vbase + (size_t)(kv0 + r) * 128 + sg);
            bf16x8 w0 = vs[0], w1 = vs[1], w2 = vs[2], w3 = vs[3];
#pragma unroll
            for (int i = 0; i < 8; ++i) {
                Vsl[(sg + i)      * 72 + r] = w0[i];
                Vsl[(sg + 8 + i)  * 72 + r] = w1[i];
                Vsl[(sg + 16 + i) * 72 + r] = w2[i];
                Vsl[(sg + 24 + i) * 72 + r] = w3[i];
            }
        }
        __syncthreads();

        // ---- S = Q K^T : 4 kv-ntiles x 4 d-chunks ----
        f32x4 sacc[4];
#pragma unroll
        for (int nt = 0; nt < 4; ++nt) sacc[nt] = vzero;
#pragma unroll
        for (int nt = 0; nt < 4; ++nt)
#pragma unroll
            for (int kb = 0; kb < 4; ++kb)
                sacc[nt] = __builtin_amdgcn_mfma_f32_16x16x32_bf16(
                    qf[kb],
                    *(const bf16x8*)(&Ksl[(nt * 16 + l15) * 136 + kb * 32 + quad * 8]),
                    sacc[nt], 0, 0, 0);

        // ---- causal mask + online softmax (rows = quad*4+i within wave) ----
        const int qr0 = qt * 64 + wave * 16 + quad * 4;
        float p[4][4];
        float mt_[4];
#pragma unroll
        for (int i = 0; i < 4; ++i) mt_[i] = -INFINITY;
#pragma unroll
        for (int nt = 0; nt < 4; ++nt) {
            const int kvc = kv0 + nt * 16 + l15;
#pragma unroll
            for (int i = 0; i < 4; ++i) {
                float sc = sacc[nt][i];
                if (kvc > qr0 + i) sc = -INFINITY;
                p[nt][i] = sc;
                mt_[i] = fmaxf(mt_[i], sc);
            }
        }
#pragma unroll
        for (int off = 1; off < 16; off <<= 1)
#pragma unroll
            for (int i = 0; i < 4; ++i)
                mt_[i] = fmaxf(mt_[i], __shfl_xor(mt_[i], off, 64));

        float alpha[4];
#pragma unroll
        for (int i = 0; i < 4; ++i) {
            const float mnew = fmaxf(m_i[i], mt_[i]);
            alpha[i] = __expf(m_i[i] - mnew);  // first iter: exp(-inf)=0, mnew finite
            m_i[i] = mnew;
        }
        float rs[4] = {0.f, 0.f, 0.f, 0.f};
#pragma unroll
        for (int nt = 0; nt < 4; ++nt)
#pragma unroll
            for (int i = 0; i < 4; ++i) {
                const float pv = __expf(p[nt][i] - m_i[i]);
                rs[i] += pv;
                Psl[wave * 1152 + (quad * 4 + i) * 72 + nt * 16 + l15] = (bf16)pv;
            }
#pragma unroll
        for (int off = 1; off < 16; off <<= 1)
#pragma unroll
            for (int i = 0; i < 4; ++i)
                rs[i] += __shfl_xor(rs[i], off, 64);
#pragma unroll
        for (int i = 0; i < 4; ++i) l_i[i] = l_i[i] * alpha[i] + rs[i];
#pragma unroll
        for (int dn = 0; dn < 8; ++dn)
#pragma unroll
            for (int i = 0; i < 4; ++i) acc_o[dn][i] *= alpha[i];

        __syncthreads();  // P store -> P load (wave-local; barrier keeps it simple+safe)

        // ---- O += P V : P in A-layout from LDS, V transposed ----
        bf16x8 pf[2];
#pragma unroll
        for (int k2 = 0; k2 < 2; ++k2)
            pf[k2] = *(const bf16x8*)(&Psl[wave * 1152 + l15 * 72 + k2 * 32 + quad * 8]);
#pragma unroll
        for (int dn = 0; dn < 8; ++dn)
#pragma unroll
            for (int k2 = 0; k2 < 2; ++k2)
                acc_o[dn] = __builtin_amdgcn_mfma_f32_16x16x32_bf16(
                    pf[k2],
                    *(const bf16x8*)(&Vsl[(dn * 16 + l15) * 72 + k2 * 32 + quad * 8]),
                    acc_o[dn], 0, 0, 0);

        __syncthreads();  // protect K/V LDS before next staging
    }

    // ---- epilogue: write [B, S, H, HD] (row-major 4096x4096 for out proj) ----
#pragma unroll
    for (int i = 0; i < 4; ++i) l_i[i] = 1.f / l_i[i];
#pragma unroll
    for (int dn = 0; dn < 8; ++dn)
#pragma unroll
        for (int i = 0; i < 4; ++i) {
            const int s = qt * 64 + wave * 16 + quad * 4 + i;
            o[(((size_t)b * 2048 + s) * 32 + h) * 128 + dn * 16 + l15] =
                (bf16)(acc_o[dn][i] * l_i[i]);
        }
}

// ---------------------------------------------------------------------------
extern "C" void kernel_launch(void* const* d_in, const int* in_sizes, int n_in,
                              void* d_out, int out_size, void* d_ws, size_t ws_size,
                              hipStream_t stream)
{
    (void)in_sizes; (void)n_in; (void)out_size; (void)ws_size;
    const float* hidden = (const float*)d_in[0];
    const int*   pos    = (const int*)d_in[1];
    const float* wq     = (const float*)d_in[2];
    const float* bq     = (const float*)d_in[3];
    const float* wk     = (const float*)d_in[4];
    const float* bk     = (const float*)d_in[5];
    const float* wv     = (const float*)d_in[6];
    const float* bv     = (const float*)d_in[7];
    const float* wo     = (const float*)d_in[8];
    float* out = (float*)d_out;

    // workspace layout (bytes); attn output aliases q_pre (dead after rope_q)
    char* ws = (char*)d_ws;
    bf16* q_pre  = (bf16*)(ws);               // [4096, 4096] 33.5 MB
    bf16* k_pre  = (bf16*)(ws + 33554432);    // [4096, 1024]  8.4 MB
    bf16* v_pre  = (bf16*)(ws + 41943040);    // [4096, 1024]  8.4 MB
    bf16* q_rope = (bf16*)(ws + 50331648);    // [B,H,S,HD]   33.5 MB
    bf16* k_rope = (bf16*)(ws + 83886080);    // [B,KV,S,HD]   8.4 MB
    bf16* v_b    = (bf16*)(ws + 92274688);    // [B,KV,S,HD]   8.4 MB
    bf16* attn_o = (bf16*)(ws);               // alias q_pre   33.5 MB  (total ~96 MB)

    // 1) QKV projection (N = 4096 | 1024 | 1024 selected by n-tile)
    gemm_kernel<0><<<dim3(48, 32), 256, 0, stream>>>(
        hidden, nullptr, wq, bq, wk, bk, wv, bv, q_pre, k_pre, v_pre, nullptr);

    // 2) RoPE + transpose; Q gets 1/sqrt(128) folded in
    rope_kernel<32, 5><<<32768, 256, 0, stream>>>(q_pre, pos, q_rope, 0.08838834764831845f);
    rope_kernel<8, 3><<<8192, 256, 0, stream>>>(k_pre, pos, k_rope, 1.0f);
    conv_v_kernel<<<16384, 256, 0, stream>>>(v_pre, v_b);

    // 3) causal GQA flash attention
    attn_kernel<<<2048, 256, 0, stream>>>(q_rope, k_rope, v_b, attn_o);

    // 4) output projection -> d_out (fp32)
    gemm_kernel<1><<<dim3(32, 32), 256, 0, stream>>>(
        nullptr, attn_o, wo, nullptr, nullptr, nullptr, nullptr, nullptr,
        nullptr, nullptr, nullptr, out);
}

// Round 2
// 1235.515 us; speedup vs baseline: 1.2906x; 1.2906x over previous
//
#include <hip/hip_runtime.h>
#include <hip/hip_bf16.h>
#include <math.h>

// Problem: B=2, S=2048, D=4096, H=32, KV=8, HD=128, N_REP=4, theta=1e6
// Inputs (fp32 unless noted): hidden(2,2048,4096), position_ids(int32 2,2048),
//   wq(4096,4096), bq(4096), wk(4096,1024), bk(1024), wv(4096,1024), bv(1024),
//   wo(4096,4096). Output fp32 (2,2048,4096).

typedef __bf16 bf16;
typedef __attribute__((ext_vector_type(8))) __bf16 bf16x8;
typedef __attribute__((ext_vector_type(4))) float f32x4;

// async global->LDS, 16 B per lane; LDS dest = wave-uniform base + lane*16
__device__ __forceinline__ void glds16(const void* g, void* l) {
    __builtin_amdgcn_global_load_lds(
        (const __attribute__((address_space(1))) void*)g,
        (__attribute__((address_space(3))) void*)l, 16, 0, 0);
}

// ---------------------------------------------------------------------------
// Weight transpose + fp32->bf16: in [K=4096][N] row-major -> out [N][4096].
// Tile 64(k) x 32(n), 256 threads. Output rows written as bf16x8 (16 B/lane).
// ---------------------------------------------------------------------------
__global__ __launch_bounds__(256) void transpose_conv_kernel(
    const float* __restrict__ in, bf16* __restrict__ out, int N)
{
    __shared__ bf16 tile[32 * 68];   // [n][k], stride 68 keeps conflicts ~2-way
    const int n0 = blockIdx.x * 32, k0 = blockIdx.y * 64;
    const int t = threadIdx.x;
    const int nn = t & 31, kk0 = (t >> 5) * 8;
#pragma unroll
    for (int j = 0; j < 8; ++j)
        tile[nn * 68 + kk0 + j] = (bf16)in[(size_t)(k0 + kk0 + j) * N + n0 + nn];
    __syncthreads();
    const int n2 = t >> 3, c = (t & 7) * 8;
    *(bf16x8*)(out + (size_t)(n0 + n2) * 4096 + k0 + c) = *(const bf16x8*)(&tile[n2 * 68 + c]);
}

// ---------------------------------------------------------------------------
// GEMM m97-style: C[M=4096,N] = A[4096,4096] * B^T[N][4096] (+bias).
// Tile 128x128, BK=32, 256 threads = 4 waves (2x2), wave = 64x64 = 4x4 MFMAs.
// B^T staged via global_load_lds(16) into unpadded LDS [128 n][32 k].
// MODE 0: A fp32 (VALU convert, padded LDS stride 34); epilogue routes
//         q -> [b,s,h,d] and k/v scattered to [b,kv,s,d]; +bias; bf16 out.
// MODE 1: A bf16 via global_load_lds (unpadded); fp32 out (d_out).
// ---------------------------------------------------------------------------
template <int MODE>
__global__ __launch_bounds__(256) void gemm_kernel(
    const float* __restrict__ A_f32, const bf16* __restrict__ A_bf16,
    const bf16* __restrict__ BqT, const bf16* __restrict__ BkT, const bf16* __restrict__ BvT,
    const float* __restrict__ b_q, const float* __restrict__ b_k, const float* __restrict__ b_v,
    bf16* __restrict__ q_out, bf16* __restrict__ kv_k, bf16* __restrict__ kv_v,
    float* __restrict__ f_out)
{
    constexpr int LDA = (MODE == 0) ? 34 : 32;
    __shared__ bf16 As[128 * LDA];
    __shared__ bf16 Bs[128 * 32];

    const int nt = blockIdx.x, mt = blockIdx.y;
    const int tid = threadIdx.x;
    const int wave = tid >> 6, lane = tid & 63;
    const int l15 = lane & 15, quad = lane >> 4;
    const int wm = (wave >> 1) * 64, wn = (wave & 1) * 64;

    const bf16* BT;
    const float* bias = nullptr;
    int sel = 0, ncol0;
    if (MODE == 0) {
        if (nt < 32)      { BT = BqT; bias = b_q; sel = 0; ncol0 = nt * 128; }
        else if (nt < 40) { BT = BkT; bias = b_k; sel = 1; ncol0 = (nt - 32) * 128; }
        else              { BT = BvT; bias = b_v; sel = 2; ncol0 = (nt - 40) * 128; }
    } else {
        BT = BqT; ncol0 = nt * 128;
    }
    const int row0 = mt * 128;

    const f32x4 vzero = {0.f, 0.f, 0.f, 0.f};
    f32x4 acc[4][4];
#pragma unroll
    for (int mi = 0; mi < 4; ++mi)
#pragma unroll
        for (int ni = 0; ni < 4; ++ni) acc[mi][ni] = vzero;

    const int a_row = tid >> 1, a_seg = (tid & 1) * 16;   // MODE0 VALU staging
    const int g_row = lane >> 2, g_seg = (lane & 3) * 8;  // glds lane mapping

    for (int k0 = 0; k0 < 4096; k0 += 32) {
        // ---- stage A tile (128x32) ----
        if (MODE == 0) {
            const float4* src = (const float4*)(A_f32 + (size_t)(row0 + a_row) * 4096 + k0 + a_seg);
            float4 f0 = src[0], f1 = src[1], f2 = src[2], f3 = src[3];
            bf16x8 p0, p1;
            p0[0] = (bf16)f0.x; p0[1] = (bf16)f0.y; p0[2] = (bf16)f0.z; p0[3] = (bf16)f0.w;
            p0[4] = (bf16)f1.x; p0[5] = (bf16)f1.y; p0[6] = (bf16)f1.z; p0[7] = (bf16)f1.w;
            p1[0] = (bf16)f2.x; p1[1] = (bf16)f2.y; p1[2] = (bf16)f2.z; p1[3] = (bf16)f2.w;
            p1[4] = (bf16)f3.x; p1[5] = (bf16)f3.y; p1[6] = (bf16)f3.z; p1[7] = (bf16)f3.w;
            *(bf16x8*)(&As[a_row * LDA + a_seg]) = p0;
            *(bf16x8*)(&As[a_row * LDA + a_seg + 8]) = p1;
        } else {
#pragma unroll
            for (int c = 0; c < 2; ++c)
                glds16(A_bf16 + (size_t)(row0 + wave * 32 + c * 16 + g_row) * 4096 + k0 + g_seg,
                       &As[(wave * 32 + c * 16) * 32]);
        }
        // ---- stage B^T tile (128 n-rows x 32 k) via glds ----
#pragma unroll
        for (int c = 0; c < 2; ++c)
            glds16(BT + (size_t)(ncol0 + wave * 32 + c * 16 + g_row) * 4096 + k0 + g_seg,
                   &Bs[(wave * 32 + c * 16) * 32]);
        __syncthreads();

        bf16x8 af[4], bfv[4];
#pragma unroll
        for (int mi = 0; mi < 4; ++mi)
            af[mi] = *(const bf16x8*)(&As[(wm + mi * 16 + l15) * LDA + quad * 8]);
#pragma unroll
        for (int ni = 0; ni < 4; ++ni)
            bfv[ni] = *(const bf16x8*)(&Bs[(wn + ni * 16 + l15) * 32 + quad * 8]);
#pragma unroll
        for (int mi = 0; mi < 4; ++mi)
#pragma unroll
            for (int ni = 0; ni < 4; ++ni)
                acc[mi][ni] = __builtin_amdgcn_mfma_f32_16x16x32_bf16(af[mi], bfv[ni], acc[mi][ni], 0, 0, 0);
        __syncthreads();
    }

    // ---- epilogue: C row = quad*4+reg, col = l15 (m89-verified) ----
#pragma unroll
    for (int mi = 0; mi < 4; ++mi)
#pragma unroll
        for (int ni = 0; ni < 4; ++ni)
#pragma unroll
            for (int i = 0; i < 4; ++i) {
                const int gr = row0 + wm + mi * 16 + quad * 4 + i;
                const int gc = ncol0 + wn + ni * 16 + l15;
                float vv = acc[mi][ni][i];
                if (MODE == 1) {
                    f_out[(size_t)gr * 4096 + gc] = vv;
                } else {
                    vv += bias[gc];
                    if (sel == 0) {
                        q_out[(size_t)gr * 4096 + gc] = (bf16)vv;  // [b,s,h,d]
                    } else {
                        bf16* dst = (sel == 1) ? kv_k : kv_v;      // [b,kv,s,d]
                        dst[(size_t)((gr >> 11) * 8 + (gc >> 7)) * 262144 +
                            (size_t)(gr & 2047) * 128 + (gc & 127)] = (bf16)vv;
                    }
                }
            }
}

// ---------------------------------------------------------------------------
// In-place RoPE. Pair (d, d+64) handled by one thread -> in-place safe.
// Q layout [b,s,h,128] with scale 1/sqrt(128) folded; K layout [b,kv,s,128].
// ---------------------------------------------------------------------------
__global__ __launch_bounds__(256) void rope_q_kernel(
    bf16* __restrict__ q, const int* __restrict__ pos_ids)
{
    const int idx = blockIdx.x * 256 + threadIdx.x;
    const int d = idx & 63, h = (idx >> 6) & 31, tok = idx >> 11;
    const float posv = (float)pos_ids[tok];
    const float fr = exp2f((float)d * (-19.931568569324174f / 64.f));
    float sn, cs;
    sincosf(posv * fr, &sn, &cs);
    bf16* xp = q + (size_t)tok * 4096 + h * 128 + d;
    const float x1 = (float)xp[0], x2 = (float)xp[64];
    const float scale = 0.08838834764831845f;
    xp[0]  = (bf16)((x1 * cs - x2 * sn) * scale);
    xp[64] = (bf16)((x1 * sn + x2 * cs) * scale);
}

__global__ __launch_bounds__(256) void rope_k_kernel(
    bf16* __restrict__ k, const int* __restrict__ pos_ids)
{
    const int idx = blockIdx.x * 256 + threadIdx.x;
    const int d = idx & 63, s = (idx >> 6) & 2047, bk = idx >> 17;
    const int b = bk >> 3;
    const float posv = (float)pos_ids[b * 2048 + s];
    const float fr = exp2f((float)d * (-19.931568569324174f / 64.f));
    float sn, cs;
    sincosf(posv * fr, &sn, &cs);
    bf16* xp = k + ((size_t)bk * 2048 + s) * 128 + d;
    const float x1 = (float)xp[0], x2 = (float)xp[64];
    xp[0]  = (bf16)(x1 * cs - x2 * sn);
    xp[64] = (bf16)(x1 * sn + x2 * cs);
}

// ---------------------------------------------------------------------------
// Flash attention, causal, GQA (4 q-heads / kv-head), bf16 MFMA 16x16x32.
// Block = 4 waves; wave owns 16 q rows (BQ=64/block). KV tiles of 64.
// Q read from [b,s,h,d]; K/V from [b,kv,s,d]; out -> [b,s,h,d].
// ---------------------------------------------------------------------------
__global__ __launch_bounds__(256) void attn_kernel(
    const bf16* __restrict__ q, const bf16* __restrict__ k,
    const bf16* __restrict__ v, bf16* __restrict__ o)
{
    __shared__ bf16 Ksl[64 * 136];      // [kv][d], stride 136
    __shared__ bf16 Vsl[128 * 72];      // transposed [d][kv], stride 72
    __shared__ bf16 Psl[4 * 16 * 72];   // per-wave [qrow][kv], stride 72

    const int qt = blockIdx.x & 31;
    const int h  = (blockIdx.x >> 5) & 31;
    const int b  = blockIdx.x >> 10;
    const int kvh = h >> 2;
    const int tid = threadIdx.x;
    const int wave = tid >> 6, lane = tid & 63;
    const int l15 = lane & 15, quad = lane >> 4;

    // Q fragment (A-layout: row=l15, k=quad*8+j); Q layout [b,s,h,d]
    const bf16* qrow = q + ((size_t)(b * 2048 + qt * 64 + wave * 16 + l15) * 32 + h) * 128;
    bf16x8 qf[4];
#pragma unroll
    for (int kb = 0; kb < 4; ++kb)
        qf[kb] = *(const bf16x8*)(qrow + kb * 32 + quad * 8);

    const f32x4 vzero = {0.f, 0.f, 0.f, 0.f};
    f32x4 acc_o[8];
#pragma unroll
    for (int i = 0; i < 8; ++i) acc_o[i] = vzero;
    float m_i[4], l_i[4];
#pragma unroll
    for (int i = 0; i < 4; ++i) { m_i[i] = -INFINITY; l_i[i] = 0.f; }

    const bf16* kbase = k + (size_t)(b * 8 + kvh) * 2048 * 128;
    const bf16* vbase = v + (size_t)(b * 8 + kvh) * 2048 * 128;

    const int r = tid >> 2, sg = (tid & 3) * 32;  // staging: 64 rows x 4 segs of 32

    for (int t = 0; t <= qt; ++t) {
        const int kv0 = t * 64;
        {
            const bf16x8* ks = (const bf16x8*)(kbase + (size_t)(kv0 + r) * 128 + sg);
            bf16x8* kd = (bf16x8*)(&Ksl[r * 136 + sg]);
            kd[0] = ks[0]; kd[1] = ks[1]; kd[2] = ks[2]; kd[3] = ks[3];
            const bf16x8* vs = (const bf16x8*)(vbase + (size_t)(kv0 + r) * 128 + sg);
            bf16x8 w0 = vs[0], w1 = vs[1], w2 = vs[2], w3 = vs[3];
#pragma unroll
            for (int i = 0; i < 8; ++i) {
                Vsl[(sg + i)      * 72 + r] = w0[i];
                Vsl[(sg + 8 + i)  * 72 + r] = w1[i];
                Vsl[(sg + 16 + i) * 72 + r] = w2[i];
                Vsl[(sg + 24 + i) * 72 + r] = w3[i];
            }
        }
        __syncthreads();

        // ---- S = Q K^T ----
        f32x4 sacc[4];
#pragma unroll
        for (int nt = 0; nt < 4; ++nt) sacc[nt] = vzero;
#pragma unroll
        for (int nt = 0; nt < 4; ++nt)
#pragma unroll
            for (int kb = 0; kb < 4; ++kb)
                sacc[nt] = __builtin_amdgcn_mfma_f32_16x16x32_bf16(
                    qf[kb],
                    *(const bf16x8*)(&Ksl[(nt * 16 + l15) * 136 + kb * 32 + quad * 8]),
                    sacc[nt], 0, 0, 0);

        // ---- causal mask + online softmax ----
        const int qr0 = qt * 64 + wave * 16 + quad * 4;
        float p[4][4];
        float mt_[4];
#pragma unroll
        for (int i = 0; i < 4; ++i) mt_[i] = -INFINITY;
#pragma unroll
        for (int nt = 0; nt < 4; ++nt) {
            const int kvc = kv0 + nt * 16 + l15;
#pragma unroll
            for (int i = 0; i < 4; ++i) {
                float sc = sacc[nt][i];
                if (kvc > qr0 + i) sc = -INFINITY;
                p[nt][i] = sc;
                mt_[i] = fmaxf(mt_[i], sc);
            }
        }
#pragma unroll
        for (int off = 1; off < 16; off <<= 1)
#pragma unroll
            for (int i = 0; i < 4; ++i)
                mt_[i] = fmaxf(mt_[i], __shfl_xor(mt_[i], off, 64));

        float alpha[4];
#pragma unroll
        for (int i = 0; i < 4; ++i) {
            const float mnew = fmaxf(m_i[i], mt_[i]);
            alpha[i] = __expf(m_i[i] - mnew);
            m_i[i] = mnew;
        }
        float rs[4] = {0.f, 0.f, 0.f, 0.f};
#pragma unroll
        for (int nt = 0; nt < 4; ++nt)
#pragma unroll
            for (int i = 0; i < 4; ++i) {
                const float pv = __expf(p[nt][i] - m_i[i]);
                rs[i] += pv;
                Psl[wave * 1152 + (quad * 4 + i) * 72 + nt * 16 + l15] = (bf16)pv;
            }
#pragma unroll
        for (int off = 1; off < 16; off <<= 1)
#pragma unroll
            for (int i = 0; i < 4; ++i)
                rs[i] += __shfl_xor(rs[i], off, 64);
#pragma unroll
        for (int i = 0; i < 4; ++i) l_i[i] = l_i[i] * alpha[i] + rs[i];
#pragma unroll
        for (int dn = 0; dn < 8; ++dn)
#pragma unroll
            for (int i = 0; i < 4; ++i) acc_o[dn][i] *= alpha[i];

        __syncthreads();

        // ---- O += P V ----
        bf16x8 pf[2];
#pragma unroll
        for (int k2 = 0; k2 < 2; ++k2)
            pf[k2] = *(const bf16x8*)(&Psl[wave * 1152 + l15 * 72 + k2 * 32 + quad * 8]);
#pragma unroll
        for (int dn = 0; dn < 8; ++dn)
#pragma unroll
            for (int k2 = 0; k2 < 2; ++k2)
                acc_o[dn] = __builtin_amdgcn_mfma_f32_16x16x32_bf16(
                    pf[k2],
                    *(const bf16x8*)(&Vsl[(dn * 16 + l15) * 72 + k2 * 32 + quad * 8]),
                    acc_o[dn], 0, 0, 0);

        __syncthreads();
    }

    // ---- epilogue -> [b,s,h,d] ----
#pragma unroll
    for (int i = 0; i < 4; ++i) l_i[i] = 1.f / l_i[i];
#pragma unroll
    for (int dn = 0; dn < 8; ++dn)
#pragma unroll
        for (int i = 0; i < 4; ++i) {
            const int s = qt * 64 + wave * 16 + quad * 4 + i;
            o[(((size_t)b * 2048 + s) * 32 + h) * 128 + dn * 16 + l15] =
                (bf16)(acc_o[dn][i] * l_i[i]);
        }
}

// ---------------------------------------------------------------------------
extern "C" void kernel_launch(void* const* d_in, const int* in_sizes, int n_in,
                              void* d_out, int out_size, void* d_ws, size_t ws_size,
                              hipStream_t stream)
{
    (void)in_sizes; (void)n_in; (void)out_size; (void)ws_size;
    const float* hidden = (const float*)d_in[0];
    const int*   pos    = (const int*)d_in[1];
    const float* wq     = (const float*)d_in[2];
    const float* bq_    = (const float*)d_in[3];
    const float* wk     = (const float*)d_in[4];
    const float* bk_    = (const float*)d_in[5];
    const float* wv     = (const float*)d_in[6];
    const float* bv_    = (const float*)d_in[7];
    const float* wo     = (const float*)d_in[8];
    float* out = (float*)d_out;

    // workspace: 100,663,296 B total (same proven footprint as R1), region reuse:
    char* ws = (char*)d_ws;
    bf16* wqT   = (bf16*)(ws);                 // R1 33.5 MB -> attn_o after QKV gemm
    bf16* wkT   = (bf16*)(ws + 33554432);      // R2  8.4 MB
    bf16* wvT   = (bf16*)(ws + 41943040);      // R3  8.4 MB
    bf16* q_pre = (bf16*)(ws + 50331648);      // R4 33.5 MB [b,s,h,d] -> woT after attn
    bf16* k_t   = (bf16*)(ws + 83886080);      // R5  8.4 MB [b,kv,s,d]
    bf16* v_t   = (bf16*)(ws + 92274688);      // R6  8.4 MB [b,kv,s,d]
    bf16* attn_o = wqT;
    bf16* woT    = q_pre;

    // 1) weight transposes (fp32 [K][N] -> bf16 [N][K])
    transpose_conv_kernel<<<dim3(128, 64), 256, 0, stream>>>(wq, wqT, 4096);
    transpose_conv_kernel<<<dim3(32, 64), 256, 0, stream>>>(wk, wkT, 1024);
    transpose_conv_kernel<<<dim3(32, 64), 256, 0, stream>>>(wv, wvT, 1024);

    // 2) QKV projection; K/V written directly to [b,kv,s,d]
    gemm_kernel<0><<<dim3(48, 32), 256, 0, stream>>>(
        hidden, nullptr, wqT, wkT, wvT, bq_, bk_, bv_, q_pre, k_t, v_t, nullptr);

    // 3) in-place RoPE (Q gets 1/sqrt(128) folded)
    rope_q_kernel<<<32768, 256, 0, stream>>>(q_pre, pos);
    rope_k_kernel<<<8192, 256, 0, stream>>>(k_t, pos);

    // 4) causal GQA flash attention -> attn_o [b,s,h,d] (reuses wqT region)
    attn_kernel<<<2048, 256, 0, stream>>>(q_pre, k_t, v_t, attn_o);

    // 5) transpose wo into q_pre region (q dead after attn)
    transpose_conv_kernel<<<dim3(128, 64), 256, 0, stream>>>(wo, woT, 4096);

    // 6) output projection -> d_out (fp32), full m97 glds path
    gemm_kernel<1><<<dim3(32, 32), 256, 0, stream>>>(
        nullptr, attn_o, woT, nullptr, nullptr, nullptr, nullptr, nullptr,
        nullptr, nullptr, nullptr, out);
}

// Round 3
// 984.102 us; speedup vs baseline: 1.6203x; 1.2555x over previous
//
#include <hip/hip_runtime.h>
#include <hip/hip_bf16.h>
#include <math.h>

// Problem: B=2, S=2048, D=4096, H=32, KV=8, HD=128, N_REP=4, theta=1e6
// Output fp32 (2,2048,4096).

typedef __bf16 bf16;
typedef __attribute__((ext_vector_type(8))) __bf16 bf16x8;
typedef __attribute__((ext_vector_type(4))) float f32x4;

// async global->LDS, 16 B per lane; LDS dest = wave-uniform base + lane*16
__device__ __forceinline__ void glds16(const void* g, void* l) {
    __builtin_amdgcn_global_load_lds(
        (const __attribute__((address_space(1))) void*)g,
        (__attribute__((address_space(3))) void*)l, 16, 0, 0);
}

// ---------------------------------------------------------------------------
// fp32 -> bf16 elementwise convert (hidden), 8 elems/thread
// ---------------------------------------------------------------------------
__global__ __launch_bounds__(256) void convert_kernel(
    const float* __restrict__ in, bf16* __restrict__ out)
{
    const size_t i0 = ((size_t)blockIdx.x * 256 + threadIdx.x) * 8;
    const float4 a = *(const float4*)(in + i0);
    const float4 b = *(const float4*)(in + i0 + 4);
    bf16x8 p;
    p[0] = (bf16)a.x; p[1] = (bf16)a.y; p[2] = (bf16)a.z; p[3] = (bf16)a.w;
    p[4] = (bf16)b.x; p[5] = (bf16)b.y; p[6] = (bf16)b.z; p[7] = (bf16)b.w;
    *(bf16x8*)(out + i0) = p;
}

// ---------------------------------------------------------------------------
// Weight transpose + fp32->bf16: in [K=4096][N] row-major -> out [N][4096].
// ---------------------------------------------------------------------------
__global__ __launch_bounds__(256) void transpose_conv_kernel(
    const float* __restrict__ in, bf16* __restrict__ out, int N)
{
    __shared__ bf16 tile[32 * 68];
    const int n0 = blockIdx.x * 32, k0 = blockIdx.y * 64;
    const int t = threadIdx.x;
    const int nn = t & 31, kk0 = (t >> 5) * 8;
#pragma unroll
    for (int j = 0; j < 8; ++j)
        tile[nn * 68 + kk0 + j] = (bf16)in[(size_t)(k0 + kk0 + j) * N + n0 + nn];
    __syncthreads();
    const int n2 = t >> 3, c = (t & 7) * 8;
    *(bf16x8*)(out + (size_t)(n0 + n2) * 4096 + k0 + c) = *(const bf16x8*)(&tile[n2 * 68 + c]);
}

// ---------------------------------------------------------------------------
// GEMM m97-style: C[4096,N] = A[4096,4096] * B^T[N][4096] (+bias).
// Tile 128x128, BK=32, 4 waves (2x2), wave 64x64 (4x4 MFMAs), glds staging.
// EPI 0: bias + q->[b,s,h,d], k/v scattered ->[b,kv,s,d] (bf16)
// EPI 1: fp32 out.  AF32: A staged from fp32 via VALU (fallback path only).
// ---------------------------------------------------------------------------
template <int EPI, int AF32>
__global__ __launch_bounds__(256) void gemm_kernel(
    const float* __restrict__ A_f32, const bf16* __restrict__ A_bf16,
    const bf16* __restrict__ BqT, const bf16* __restrict__ BkT, const bf16* __restrict__ BvT,
    const float* __restrict__ b_q, const float* __restrict__ b_k, const float* __restrict__ b_v,
    bf16* __restrict__ q_out, bf16* __restrict__ kv_k, bf16* __restrict__ kv_v,
    float* __restrict__ f_out)
{
    constexpr int LDA = AF32 ? 34 : 32;
    __shared__ bf16 As[128 * LDA];
    __shared__ bf16 Bs[128 * 32];

    const int nt = blockIdx.x, mt = blockIdx.y;
    const int tid = threadIdx.x;
    const int wave = tid >> 6, lane = tid & 63;
    const int l15 = lane & 15, quad = lane >> 4;
    const int wm = (wave >> 1) * 64, wn = (wave & 1) * 64;

    const bf16* BT;
    const float* bias = nullptr;
    int sel = 0, ncol0;
    if (EPI == 0) {
        if (nt < 32)      { BT = BqT; bias = b_q; sel = 0; ncol0 = nt * 128; }
        else if (nt < 40) { BT = BkT; bias = b_k; sel = 1; ncol0 = (nt - 32) * 128; }
        else              { BT = BvT; bias = b_v; sel = 2; ncol0 = (nt - 40) * 128; }
    } else {
        BT = BqT; ncol0 = nt * 128;
    }
    const int row0 = mt * 128;

    const f32x4 vzero = {0.f, 0.f, 0.f, 0.f};
    f32x4 acc[4][4];
#pragma unroll
    for (int mi = 0; mi < 4; ++mi)
#pragma unroll
        for (int ni = 0; ni < 4; ++ni) acc[mi][ni] = vzero;

    const int a_row = tid >> 1, a_seg = (tid & 1) * 16;   // AF32 VALU staging
    const int g_row = lane >> 2, g_seg = (lane & 3) * 8;  // glds lane mapping

    for (int k0 = 0; k0 < 4096; k0 += 32) {
        // ---- stage A tile (128x32) ----
        if (AF32) {
            const float4* src = (const float4*)(A_f32 + (size_t)(row0 + a_row) * 4096 + k0 + a_seg);
            float4 f0 = src[0], f1 = src[1], f2 = src[2], f3 = src[3];
            bf16x8 p0, p1;
            p0[0] = (bf16)f0.x; p0[1] = (bf16)f0.y; p0[2] = (bf16)f0.z; p0[3] = (bf16)f0.w;
            p0[4] = (bf16)f1.x; p0[5] = (bf16)f1.y; p0[6] = (bf16)f1.z; p0[7] = (bf16)f1.w;
            p1[0] = (bf16)f2.x; p1[1] = (bf16)f2.y; p1[2] = (bf16)f2.z; p1[3] = (bf16)f2.w;
            p1[4] = (bf16)f3.x; p1[5] = (bf16)f3.y; p1[6] = (bf16)f3.z; p1[7] = (bf16)f3.w;
            *(bf16x8*)(&As[a_row * LDA + a_seg]) = p0;
            *(bf16x8*)(&As[a_row * LDA + a_seg + 8]) = p1;
        } else {
#pragma unroll
            for (int c = 0; c < 2; ++c)
                glds16(A_bf16 + (size_t)(row0 + wave * 32 + c * 16 + g_row) * 4096 + k0 + g_seg,
                       &As[(wave * 32 + c * 16) * 32]);
        }
        // ---- stage B^T tile (128 n-rows x 32 k) via glds ----
#pragma unroll
        for (int c = 0; c < 2; ++c)
            glds16(BT + (size_t)(ncol0 + wave * 32 + c * 16 + g_row) * 4096 + k0 + g_seg,
                   &Bs[(wave * 32 + c * 16) * 32]);
        __syncthreads();

        bf16x8 af[4], bfv[4];
#pragma unroll
        for (int mi = 0; mi < 4; ++mi)
            af[mi] = *(const bf16x8*)(&As[(wm + mi * 16 + l15) * LDA + quad * 8]);
#pragma unroll
        for (int ni = 0; ni < 4; ++ni)
            bfv[ni] = *(const bf16x8*)(&Bs[(wn + ni * 16 + l15) * 32 + quad * 8]);
#pragma unroll
        for (int mi = 0; mi < 4; ++mi)
#pragma unroll
            for (int ni = 0; ni < 4; ++ni)
                acc[mi][ni] = __builtin_amdgcn_mfma_f32_16x16x32_bf16(af[mi], bfv[ni], acc[mi][ni], 0, 0, 0);
        __syncthreads();
    }

    // ---- epilogue: C row = quad*4+reg, col = l15 ----
#pragma unroll
    for (int mi = 0; mi < 4; ++mi)
#pragma unroll
        for (int ni = 0; ni < 4; ++ni)
#pragma unroll
            for (int i = 0; i < 4; ++i) {
                const int gr = row0 + wm + mi * 16 + quad * 4 + i;
                const int gc = ncol0 + wn + ni * 16 + l15;
                float vv = acc[mi][ni][i];
                if (EPI == 1) {
                    f_out[(size_t)gr * 4096 + gc] = vv;
                } else {
                    vv += bias[gc];
                    if (sel == 0) {
                        q_out[(size_t)gr * 4096 + gc] = (bf16)vv;  // [b,s,h,d]
                    } else {
                        bf16* dst = (sel == 1) ? kv_k : kv_v;      // [b,kv,s,d]
                        dst[(size_t)((gr >> 11) * 8 + (gc >> 7)) * 262144 +
                            (size_t)(gr & 2047) * 128 + (gc & 127)] = (bf16)vv;
                    }
                }
            }
}

// ---------------------------------------------------------------------------
// In-place RoPE. Q [b,s,h,128] (scale folded); K [b,kv,s,128].
// ---------------------------------------------------------------------------
__global__ __launch_bounds__(256) void rope_q_kernel(
    bf16* __restrict__ q, const int* __restrict__ pos_ids)
{
    const int idx = blockIdx.x * 256 + threadIdx.x;
    const int d = idx & 63, h = (idx >> 6) & 31, tok = idx >> 11;
    const float posv = (float)pos_ids[tok];
    const float fr = exp2f((float)d * (-19.931568569324174f / 64.f));
    float sn, cs;
    sincosf(posv * fr, &sn, &cs);
    bf16* xp = q + (size_t)tok * 4096 + h * 128 + d;
    const float x1 = (float)xp[0], x2 = (float)xp[64];
    const float scale = 0.08838834764831845f;
    xp[0]  = (bf16)((x1 * cs - x2 * sn) * scale);
    xp[64] = (bf16)((x1 * sn + x2 * cs) * scale);
}

__global__ __launch_bounds__(256) void rope_k_kernel(
    bf16* __restrict__ k, const int* __restrict__ pos_ids)
{
    const int idx = blockIdx.x * 256 + threadIdx.x;
    const int d = idx & 63, s = (idx >> 6) & 2047, bk = idx >> 17;
    const int b = bk >> 3;
    const float posv = (float)pos_ids[b * 2048 + s];
    const float fr = exp2f((float)d * (-19.931568569324174f / 64.f));
    float sn, cs;
    sincosf(posv * fr, &sn, &cs);
    bf16* xp = k + ((size_t)bk * 2048 + s) * 128 + d;
    const float x1 = (float)xp[0], x2 = (float)xp[64];
    xp[0]  = (bf16)(x1 * cs - x2 * sn);
    xp[64] = (bf16)(x1 * sn + x2 * cs);
}

// ---------------------------------------------------------------------------
// Flash attention, causal, GQA. BQ=128/block, 4 waves, wave owns 32 q-rows
// (2 m-tiles). KV tiles of 64. K/V frags shared across m-tiles (joint loops).
// V staged transposed with lane=kv-row (2-way banks = free). P stride 68.
// No P barrier (wave-local LDS round-trip, lgkmcnt-ordered).
// ---------------------------------------------------------------------------
__global__ __launch_bounds__(256) void attn_kernel(
    const bf16* __restrict__ q, const bf16* __restrict__ k,
    const bf16* __restrict__ v, bf16* __restrict__ o)
{
    __shared__ bf16 Ksl[64 * 136];      // [kv][d]
    __shared__ bf16 Vsl[128 * 72];      // [d][kv]
    __shared__ bf16 Psl[4 * 16 * 68];   // per-wave [qrow][kv]

    const int qt = blockIdx.x & 15;
    const int h  = (blockIdx.x >> 4) & 31;
    const int b  = blockIdx.x >> 9;
    const int kvh = h >> 2;
    const int tid = threadIdx.x;
    const int wave = tid >> 6, lane = tid & 63;
    const int l15 = lane & 15, quad = lane >> 4;
    const int qbase = qt * 128 + wave * 32;

    // Q fragments, 2 m-tiles (A-layout: row=l15, k=quad*8+j)
    bf16x8 qf[2][4];
#pragma unroll
    for (int mi = 0; mi < 2; ++mi) {
        const bf16* qrow = q + ((size_t)(b * 2048 + qbase + mi * 16 + l15) * 32 + h) * 128;
#pragma unroll
        for (int kb = 0; kb < 4; ++kb)
            qf[mi][kb] = *(const bf16x8*)(qrow + kb * 32 + quad * 8);
    }

    const f32x4 vzero = {0.f, 0.f, 0.f, 0.f};
    f32x4 acc_o[2][8];
#pragma unroll
    for (int mi = 0; mi < 2; ++mi)
#pragma unroll
        for (int i = 0; i < 8; ++i) acc_o[mi][i] = vzero;
    float m_i[2][4], l_i[2][4];
#pragma unroll
    for (int mi = 0; mi < 2; ++mi)
#pragma unroll
        for (int i = 0; i < 4; ++i) { m_i[mi][i] = -INFINITY; l_i[mi][i] = 0.f; }

    const bf16* kbase = k + (size_t)(b * 8 + kvh) * 2048 * 128;
    const bf16* vbase = v + (size_t)(b * 8 + kvh) * 2048 * 128;

    const int kr = tid >> 2, ksg = (tid & 3) * 32;  // K staging: 64 rows x 4 segs

    const int nT = 2 * qt + 2;
    for (int t = 0; t < nT; ++t) {
        const int kv0 = t * 64;
        // ---- stage K row-major (b128, conflict-min) ----
        {
            const bf16x8* ks = (const bf16x8*)(kbase + (size_t)(kv0 + kr) * 128 + ksg);
            bf16x8* kd = (bf16x8*)(&Ksl[kr * 136 + ksg]);
            kd[0] = ks[0]; kd[1] = ks[1]; kd[2] = ks[2]; kd[3] = ks[3];
        }
        // ---- stage V transposed: wave=d-block, lane=kv row -> 2-way banks ----
        {
            const bf16x8* vs = (const bf16x8*)(vbase + (size_t)(kv0 + lane) * 128 + wave * 32);
            bf16x8 w0 = vs[0], w1 = vs[1], w2 = vs[2], w3 = vs[3];
#pragma unroll
            for (int i = 0; i < 8; ++i) {
                Vsl[(wave * 32 + i)      * 72 + lane] = w0[i];
                Vsl[(wave * 32 + 8 + i)  * 72 + lane] = w1[i];
                Vsl[(wave * 32 + 16 + i) * 72 + lane] = w2[i];
                Vsl[(wave * 32 + 24 + i) * 72 + lane] = w3[i];
            }
        }
        __syncthreads();

        if (kv0 <= qbase + 31) {  // wave has unmasked work in this tile
            // ---- S = Q K^T, joint over m-tiles (K frag read once) ----
            f32x4 sacc[2][4];
#pragma unroll
            for (int mi = 0; mi < 2; ++mi)
#pragma unroll
                for (int nt = 0; nt < 4; ++nt) sacc[mi][nt] = vzero;
#pragma unroll
            for (int nt = 0; nt < 4; ++nt)
#pragma unroll
                for (int kb = 0; kb < 4; ++kb) {
                    const bf16x8 kf = *(const bf16x8*)(&Ksl[(nt * 16 + l15) * 136 + kb * 32 + quad * 8]);
                    sacc[0][nt] = __builtin_amdgcn_mfma_f32_16x16x32_bf16(qf[0][kb], kf, sacc[0][nt], 0, 0, 0);
                    sacc[1][nt] = __builtin_amdgcn_mfma_f32_16x16x32_bf16(qf[1][kb], kf, sacc[1][nt], 0, 0, 0);
                }

            // ---- per-m-tile softmax + P write ----
            bf16x8 pf[2][2];
#pragma unroll
            for (int mi = 0; mi < 2; ++mi) {
                const int rb = qbase + mi * 16;
                if (kv0 + 63 > rb) {  // diagonal tile: apply causal mask
#pragma unroll
                    for (int nt = 0; nt < 4; ++nt) {
                        const int kvc = kv0 + nt * 16 + l15;
#pragma unroll
                        for (int i = 0; i < 4; ++i)
                            if (kvc > rb + quad * 4 + i) sacc[mi][nt][i] = -INFINITY;
                    }
                }
                float mt_[4];
#pragma unroll
                for (int i = 0; i < 4; ++i)
                    mt_[i] = fmaxf(fmaxf(sacc[mi][0][i], sacc[mi][1][i]),
                                   fmaxf(sacc[mi][2][i], sacc[mi][3][i]));
#pragma unroll
                for (int off = 1; off < 16; off <<= 1)
#pragma unroll
                    for (int i = 0; i < 4; ++i)
                        mt_[i] = fmaxf(mt_[i], __shfl_xor(mt_[i], off, 64));

                float alpha[4];
#pragma unroll
                for (int i = 0; i < 4; ++i) {
                    const float mnew = fmaxf(m_i[mi][i], mt_[i]);
                    alpha[i] = __expf(m_i[mi][i] - mnew);
                    m_i[mi][i] = mnew;
                }
                float rs[4] = {0.f, 0.f, 0.f, 0.f};
#pragma unroll
                for (int nt = 0; nt < 4; ++nt)
#pragma unroll
                    for (int i = 0; i < 4; ++i) {
                        const float pv = __expf(sacc[mi][nt][i] - m_i[mi][i]);
                        rs[i] += pv;
                        Psl[wave * 1088 + (quad * 4 + i) * 68 + nt * 16 + l15] = (bf16)pv;
                    }
#pragma unroll
                for (int off = 1; off < 16; off <<= 1)
#pragma unroll
                    for (int i = 0; i < 4; ++i)
                        rs[i] += __shfl_xor(rs[i], off, 64);
#pragma unroll
                for (int i = 0; i < 4; ++i) l_i[mi][i] = l_i[mi][i] * alpha[i] + rs[i];
#pragma unroll
                for (int dn = 0; dn < 8; ++dn)
#pragma unroll
                    for (int i = 0; i < 4; ++i) acc_o[mi][dn][i] *= alpha[i];
                // P -> A-layout frags (wave-local; lgkmcnt orders write->read)
#pragma unroll
                for (int k2 = 0; k2 < 2; ++k2)
                    pf[mi][k2] = *(const bf16x8*)(&Psl[wave * 1088 + l15 * 68 + k2 * 32 + quad * 8]);
            }

            // ---- O += P V, joint over m-tiles (V frag read once) ----
#pragma unroll
            for (int dn = 0; dn < 8; ++dn)
#pragma unroll
                for (int k2 = 0; k2 < 2; ++k2) {
                    const bf16x8 vf = *(const bf16x8*)(&Vsl[(dn * 16 + l15) * 72 + k2 * 32 + quad * 8]);
                    acc_o[0][dn] = __builtin_amdgcn_mfma_f32_16x16x32_bf16(pf[0][k2], vf, acc_o[0][dn], 0, 0, 0);
                    acc_o[1][dn] = __builtin_amdgcn_mfma_f32_16x16x32_bf16(pf[1][k2], vf, acc_o[1][dn], 0, 0, 0);
                }
        }
        __syncthreads();
    }

    // ---- epilogue -> [b,s,h,d] ----
#pragma unroll
    for (int mi = 0; mi < 2; ++mi) {
        float inv[4];
#pragma unroll
        for (int i = 0; i < 4; ++i) inv[i] = 1.f / l_i[mi][i];
#pragma unroll
        for (int dn = 0; dn < 8; ++dn)
#pragma unroll
            for (int i = 0; i < 4; ++i) {
                const int s = qbase + mi * 16 + quad * 4 + i;
                o[(((size_t)b * 2048 + s) * 32 + h) * 128 + dn * 16 + l15] =
                    (bf16)(acc_o[mi][dn][i] * inv[i]);
            }
    }
}

// ---------------------------------------------------------------------------
extern "C" void kernel_launch(void* const* d_in, const int* in_sizes, int n_in,
                              void* d_out, int out_size, void* d_ws, size_t ws_size,
                              hipStream_t stream)
{
    (void)in_sizes; (void)n_in; (void)out_size;
    const float* hidden = (const float*)d_in[0];
    const int*   pos    = (const int*)d_in[1];
    const float* wq     = (const float*)d_in[2];
    const float* bq_    = (const float*)d_in[3];
    const float* wk     = (const float*)d_in[4];
    const float* bk_    = (const float*)d_in[5];
    const float* wv     = (const float*)d_in[6];
    const float* bv_    = (const float*)d_in[7];
    const float* wo     = (const float*)d_in[8];
    float* out = (float*)d_out;

    char* ws = (char*)d_ws;
    bf16* wqT   = (bf16*)(ws);                 // 33.5 MB -> attn_o after QKV
    bf16* wkT   = (bf16*)(ws + 33554432);      //  8.4 MB
    bf16* wvT   = (bf16*)(ws + 41943040);      //  8.4 MB
    bf16* q_pre = (bf16*)(ws + 50331648);      // 33.5 MB -> woT after attn
    bf16* k_t   = (bf16*)(ws + 83886080);      //  8.4 MB [b,kv,s,d]
    bf16* v_t   = (bf16*)(ws + 92274688);      //  8.4 MB [b,kv,s,d]
    bf16* hid_b = (bf16*)(ws + 100663296);     // 33.5 MB (if ws allows)
    bf16* attn_o = wqT;
    bf16* woT    = q_pre;
    const bool have_hid = (ws_size >= 134217728);

    // 1) weight transposes (fp32 [K][N] -> bf16 [N][K])
    transpose_conv_kernel<<<dim3(128, 64), 256, 0, stream>>>(wq, wqT, 4096);
    transpose_conv_kernel<<<dim3(32, 64), 256, 0, stream>>>(wk, wkT, 1024);
    transpose_conv_kernel<<<dim3(32, 64), 256, 0, stream>>>(wv, wvT, 1024);

    // 2) QKV projection; K/V written directly to [b,kv,s,d]
    if (have_hid) {
        convert_kernel<<<8192, 256, 0, stream>>>(hidden, hid_b);
        gemm_kernel<0, 0><<<dim3(48, 32), 256, 0, stream>>>(
            nullptr, hid_b, wqT, wkT, wvT, bq_, bk_, bv_, q_pre, k_t, v_t, nullptr);
    } else {
        gemm_kernel<0, 1><<<dim3(48, 32), 256, 0, stream>>>(
            hidden, nullptr, wqT, wkT, wvT, bq_, bk_, bv_, q_pre, k_t, v_t, nullptr);
    }

    // 3) in-place RoPE (Q gets 1/sqrt(128) folded)
    rope_q_kernel<<<32768, 256, 0, stream>>>(q_pre, pos);
    rope_k_kernel<<<8192, 256, 0, stream>>>(k_t, pos);

    // 4) causal GQA flash attention (BQ=128) -> attn_o [b,s,h,d]
    attn_kernel<<<1024, 256, 0, stream>>>(q_pre, k_t, v_t, attn_o);

    // 5) transpose wo into q_pre region (q dead after attn)
    transpose_conv_kernel<<<dim3(128, 64), 256, 0, stream>>>(wo, woT, 4096);

    // 6) output projection -> d_out (fp32)
    gemm_kernel<1, 0><<<dim3(32, 32), 256, 0, stream>>>(
        nullptr, attn_o, woT, nullptr, nullptr, nullptr, nullptr, nullptr,
        nullptr, nullptr, nullptr, out);
}